// Round 10
// baseline (224.180 us; speedup 1.0000x reference)
//
#include <hip/hip_runtime.h>
#include <hip/hip_bf16.h>
#include <cstdint>

typedef float f32x4 __attribute__((ext_vector_type(4)));
typedef short bf16x8 __attribute__((ext_vector_type(8)));
typedef short short8 __attribute__((ext_vector_type(8)));

#define CIN   128
#define WIMG  56
#define HWSZ  3136      // 56*56
#define OCH   256
#define HP    58
#define WP    58

// ---- prep A: border-zero (456 blocks) + weight repack (1152 blocks), merged ----
__global__ void small_prep(const float* __restrict__ wsrc,
                           __hip_bfloat16* __restrict__ wb,
                           __hip_bfloat16* __restrict__ xb) {
    int bidx = blockIdx.x;
    if (bidx < 456) {
        int idx = bidx * 256 + threadIdx.x;   // 116736 = 32*228*16
        int c8  = idx & 15;
        int t   = idx >> 4;
        int b   = t / 228;
        int pos = t - b * 228;
        int h, w;
        if (pos < 58)       { h = 0;             w = pos; }
        else if (pos < 116) { h = 57;            w = pos - 58; }
        else if (pos < 172) { h = pos - 116 + 1; w = 0; }
        else                { h = pos - 172 + 1; w = 57; }
        uint4 z = {0, 0, 0, 0};
        *(uint4*)((char*)xb + (((size_t)(b * HP + h) * WP + w) * CIN + c8 * 8) * 2) = z;
    } else {
        int idx = (bidx - 456) * 256 + threadIdx.x;   // 294912 = 9*256*128
        int c    = idx & 127;
        int rest = idx >> 7;
        int o    = rest & 255;
        int ij   = rest >> 8;
        wb[idx] = __float2bfloat16(wsrc[((size_t)o * CIN + c) * 9 + ij]);
    }
}

// ---- prep B: x [B][C][H][W] f32 -> xb padded NHWC bf16 [B][58][58][128] ----
__global__ __launch_bounds__(256)
void cast_transpose_x(const float* __restrict__ x,
                      __hip_bfloat16* __restrict__ xb) {
    __shared__ float tile[64][33];
    const int hw0 = blockIdx.x * 32;
    const int c0  = blockIdx.y * 64;
    const int b   = blockIdx.z;

    const int lx = threadIdx.x & 31;
    const int lc = threadIdx.x >> 5;
    const float* src = x + ((size_t)(b * CIN + c0 + lc) * HWSZ) + hw0 + lx;
#pragma unroll
    for (int k = 0; k < 8; ++k)
        tile[lc + k * 8][lx] = src[(size_t)(k * 8) * HWSZ];
    __syncthreads();

    const int slot = threadIdx.x & 7;
    const int hwl  = threadIdx.x >> 3;
    int hw = hw0 + hwl;
    int h = hw / WIMG;
    int w = hw - h * WIMG;
    short8 v;
#pragma unroll
    for (int j = 0; j < 8; ++j) {
        __hip_bfloat16 hb = __float2bfloat16(tile[slot * 8 + j][hwl]);
        v[j] = *reinterpret_cast<short*>(&hb);
    }
    *(short8*)(xb + (((size_t)b * HP + (h + 1)) * WP + (w + 1)) * CIN + c0 + slot * 8) = v;
}

// ---- async global->LDS 16B ----
__device__ __forceinline__ void gload16(const void* g, void* l) {
    __builtin_amdgcn_global_load_lds(
        (const __attribute__((address_space(1))) unsigned*)g,
        (__attribute__((address_space(3))) unsigned*)l,
        16, 0, 0);
}

// ---- main: 128(M)x256(N), BK=64, 4 waves (1M x 4N), A-only LDS 2x16KB,
// B global->reg double-buffered. Small footprint => ~5 blocks/CU co-resident;
// cross-block TLP hides the per-chunk barrier drain (m114 mechanism). ----
__global__ __launch_bounds__(256)
void conv_gemm(const __hip_bfloat16* __restrict__ xb,
               const __hip_bfloat16* __restrict__ wb,
               const float* __restrict__ bias,
               float* __restrict__ out) {
    __shared__ __attribute__((aligned(16))) char smem[32768];  // 2 x A[128][64] bf16

    const int tid = threadIdx.x;
    const int wn  = tid >> 6;                 // wave = N-slice [wn*64, +64)
    const int ln  = tid & 63;

    int bid = blockIdx.x;
    bid = (bid & 7) * 98 + (bid >> 3);        // XCD swizzle: 784 = 8*98, bijective
    const int m0 = bid * 128;

    // ---- A staging (pre-swizzled source, linear LDS dest), row-keyed XOR ----
    const int srow = tid >> 3;                // 0..31
    const int cs   = tid & 7;                 // 16B slot
    const int colsrc = ((cs * 16) ^ ((srow & 7) << 4)) >> 1;
    int aOff[4];
#pragma unroll
    for (int q = 0; q < 4; ++q) {
        int row = q * 32 + srow;
        int p  = m0 + row;
        int b  = p / HWSZ;
        int hw = p - b * HWSZ;
        int h  = hw / WIMG;
        int w  = hw - h * WIMG;
        aOff[q] = ((b * HP + h) * WP + w) * CIN + colsrc;
    }
    const int ldsd = tid * 16;

#define SA4(buf, off) do {                                                    \
    gload16(xb + aOff[0] + (off), smem + (buf)*16384 +         ldsd);         \
    gload16(xb + aOff[1] + (off), smem + (buf)*16384 +  4096 + ldsd);         \
    gload16(xb + aOff[2] + (off), smem + (buf)*16384 +  8192 + ldsd);         \
    gload16(xb + aOff[3] + (off), smem + (buf)*16384 + 12288 + ldsd);         \
} while (0)

    // ---- compute-side constants ----
    const int fr  = ln & 15;
    const int kby = (ln >> 4) * 16;
    const int swz = (ln & 7) << 4;

    // per-lane B fragment base (R7-verified mapping)
    const __hip_bfloat16* bbase = wb + (wn * 64 + fr) * CIN + ((ln >> 4) << 3);

    f32x4 acc[8][4] = {};
    bf16x8 afA[8], afB[8], bqE[4][2], bqO[4][2];

#define LOADB(dst, toff) do {                                                 \
    _Pragma("unroll") for (int ni = 0; ni < 4; ++ni)                          \
    _Pragma("unroll") for (int kk = 0; kk < 2; ++kk)                          \
        dst[ni][kk] = *(const bf16x8*)(bbase + (toff) + ni*(16*CIN) + kk*32); \
} while (0)

#define DS8(dst, buf, kk) do {                                                \
    _Pragma("unroll") for (int mi = 0; mi < 8; ++mi)                          \
        dst[mi] = *(const bf16x8*)(smem + (buf)*16384 +                       \
            (mi*16 + fr)*128 + (((kk)*64 + kby) ^ swz));                      \
} while (0)

#define MM32(af, bq, kk) do {                                                 \
    _Pragma("unroll") for (int mi = 0; mi < 8; ++mi)                          \
    _Pragma("unroll") for (int ni = 0; ni < 4; ++ni)                          \
        acc[mi][ni] = __builtin_amdgcn_mfma_f32_16x16x32_bf16(                \
            af[mi], bq[ni][kk], acc[mi][ni], 0, 0, 0);                        \
} while (0)

    // ---- prologue: stage chunk 0 (A->buf0, B->bqE) ----
    SA4(0, 0);
    LOADB(bqE, 0);

#pragma unroll 1
    for (int s = 0; s < 18; ++s) {
        __syncthreads();                      // publishes buf[s&1] + bq(parity s)
        const int cur = s & 1;
        if (s < 17) {
            const int s1  = s + 1;
            const int ij  = s1 >> 1;
            const int ii  = ij / 3, jj = ij - 3 * ii;
            const int off = (ii * WP + jj) * CIN + ((s1 & 1) << 6);
            SA4(cur ^ 1, off);
            const int offB = ij * (OCH * CIN) + ((s1 & 1) << 6);
            if (s1 & 1) LOADB(bqO, offB); else LOADB(bqE, offB);
        }
        // compute chunk s
        DS8(afA, cur, 0);
        DS8(afB, cur, 1);
        if (cur) { MM32(afA, bqO, 0); MM32(afB, bqO, 1); }
        else     { MM32(afA, bqE, 0); MM32(afB, bqE, 1); }
    }
#undef SA4
#undef LOADB
#undef DS8
#undef MM32

    // ---- epilogue: C/D map col=ln&15 (n), row=(ln>>4)*4+reg (pixel) ----
    const int laneR4 = (ln >> 4) * 4;
    float bn[4];
#pragma unroll
    for (int ni = 0; ni < 4; ++ni)
        bn[ni] = bias[wn * 64 + ni * 16 + fr];

#pragma unroll
    for (int mi = 0; mi < 8; ++mi) {
        int p0 = m0 + mi * 16 + laneR4;       // multiple of 4; 4 | HWSZ
        int b  = p0 / HWSZ;
        int hw = p0 - b * HWSZ;
#pragma unroll
        for (int ni = 0; ni < 4; ++ni) {
            int n = wn * 64 + ni * 16 + fr;
            float4 v;
            v.x = acc[mi][ni][0] + bn[ni];
            v.y = acc[mi][ni][1] + bn[ni];
            v.z = acc[mi][ni][2] + bn[ni];
            v.w = acc[mi][ni][3] + bn[ni];
            *(float4*)(out + ((size_t)(b * OCH + n) * HWSZ + hw)) = v;
        }
    }
}

extern "C" void kernel_launch(void* const* d_in, const int* in_sizes, int n_in,
                              void* d_out, int out_size, void* d_ws, size_t ws_size,
                              hipStream_t stream) {
    const float* x    = (const float*)d_in[0];
    const float* w    = (const float*)d_in[1];
    const float* bias = (const float*)d_in[2];
    float* out = (float*)d_out;

    char* ws = (char*)d_ws;
    __hip_bfloat16* xbuf = (__hip_bfloat16*)ws;                   // 27,557,888 B
    __hip_bfloat16* wbuf = (__hip_bfloat16*)(ws + 27557888);      //    589,824 B

    small_prep<<<1608, 256, 0, stream>>>(w, wbuf, xbuf);
    cast_transpose_x<<<dim3(98, 2, 32), dim3(256), 0, stream>>>(x, xbuf);
    conv_gemm<<<784, 256, 0, stream>>>(xbuf, wbuf, bias, out);
}

// Round 11
// 126.635 us; speedup vs baseline: 1.7703x; 1.7703x over previous
//
#include <hip/hip_runtime.h>
#include <hip/hip_bf16.h>
#include <cstdint>

typedef float f32x4 __attribute__((ext_vector_type(4)));
typedef short bf16x8 __attribute__((ext_vector_type(8)));
typedef short short8 __attribute__((ext_vector_type(8)));

#define CIN   128
#define WIMG  56
#define HWSZ  3136      // 56*56
#define OCH   256
#define HP    58
#define WP    58

// ---- prep A: border-zero (456 blocks) + weight repack (1152 blocks), merged ----
__global__ void small_prep(const float* __restrict__ wsrc,
                           __hip_bfloat16* __restrict__ wb,
                           __hip_bfloat16* __restrict__ xb) {
    int bidx = blockIdx.x;
    if (bidx < 456) {
        int idx = bidx * 256 + threadIdx.x;   // 116736 = 32*228*16
        int c8  = idx & 15;
        int t   = idx >> 4;
        int b   = t / 228;
        int pos = t - b * 228;
        int h, w;
        if (pos < 58)       { h = 0;             w = pos; }
        else if (pos < 116) { h = 57;            w = pos - 58; }
        else if (pos < 172) { h = pos - 116 + 1; w = 0; }
        else                { h = pos - 172 + 1; w = 57; }
        uint4 z = {0, 0, 0, 0};
        *(uint4*)((char*)xb + (((size_t)(b * HP + h) * WP + w) * CIN + c8 * 8) * 2) = z;
    } else {
        int idx = (bidx - 456) * 256 + threadIdx.x;   // 294912 = 9*256*128
        int c    = idx & 127;
        int rest = idx >> 7;
        int o    = rest & 255;
        int ij   = rest >> 8;
        wb[idx] = __float2bfloat16(wsrc[((size_t)o * CIN + c) * 9 + ij]);
    }
}

// ---- prep B: x [B][C][H][W] f32 -> xb padded NHWC bf16 [B][58][58][128] ----
__global__ __launch_bounds__(256)
void cast_transpose_x(const float* __restrict__ x,
                      __hip_bfloat16* __restrict__ xb) {
    __shared__ float tile[64][33];
    const int hw0 = blockIdx.x * 32;
    const int c0  = blockIdx.y * 64;
    const int b   = blockIdx.z;

    const int lx = threadIdx.x & 31;
    const int lc = threadIdx.x >> 5;
    const float* src = x + ((size_t)(b * CIN + c0 + lc) * HWSZ) + hw0 + lx;
#pragma unroll
    for (int k = 0; k < 8; ++k)
        tile[lc + k * 8][lx] = src[(size_t)(k * 8) * HWSZ];
    __syncthreads();

    const int slot = threadIdx.x & 7;
    const int hwl  = threadIdx.x >> 3;
    int hw = hw0 + hwl;
    int h = hw / WIMG;
    int w = hw - h * WIMG;
    short8 v;
#pragma unroll
    for (int j = 0; j < 8; ++j) {
        __hip_bfloat16 hb = __float2bfloat16(tile[slot * 8 + j][hwl]);
        v[j] = *reinterpret_cast<short*>(&hb);
    }
    *(short8*)(xb + (((size_t)b * HP + (h + 1)) * WP + (w + 1)) * CIN + c0 + slot * 8) = v;
}

// ---- async global->LDS 16B ----
__device__ __forceinline__ void gload16(const void* g, void* l) {
    __builtin_amdgcn_global_load_lds(
        (const __attribute__((address_space(1))) unsigned*)g,
        (__attribute__((address_space(3))) unsigned*)l,
        16, 0, 0);
}

// ---- main: 256(M)x128(N) block, BK=64, 4 waves (2Mx2N), wave tile 128x64.
// Single 48KB buffer (A 32K + B 16K) -> 3 blocks/CU, grid 784 ~ 1 round.
// Per chunk: sync(data ready); read kk0 frags; MFMA; read kk1; sync(buffer
// free); stage s+1 (async gload_lds); MFMA kk1. LDS-port floor ~35us. ----
__global__ __launch_bounds__(256)
void conv_gemm(const __hip_bfloat16* __restrict__ xb,
               const __hip_bfloat16* __restrict__ wb,
               const float* __restrict__ bias,
               float* __restrict__ out) {
    __shared__ __attribute__((aligned(16))) char smem[49152];  // A[256][64] | B[128][64]

    const int tid = threadIdx.x;
    const int wv  = tid >> 6;
    const int ln  = tid & 63;

    int bid = blockIdx.x;
    bid = (bid & 7) * 98 + (bid >> 3);        // XCD swizzle: 784 = 8*98, bijective
    const int mt = bid >> 1;
    const int nt = bid & 1;
    const int m0 = mt * 256;
    const int n0 = nt * 128;

    // ---- staging addresses (pre-swizzled source, linear LDS dest) ----
    const int srow = tid >> 3;                // 0..31
    const int cs   = tid & 7;                 // 16B slot
    const int colsrc = ((cs * 16) ^ ((srow & 7) << 4)) >> 1;
    int aOff[8], bOff[4];
#pragma unroll
    for (int q = 0; q < 8; ++q) {
        int row = q * 32 + srow;              // 0..255
        int p  = m0 + row;
        int b  = p / HWSZ;
        int hw = p - b * HWSZ;
        int h  = hw / WIMG;
        int w  = hw - h * WIMG;
        aOff[q] = ((b * HP + h) * WP + w) * CIN + colsrc;
    }
#pragma unroll
    for (int q = 0; q < 4; ++q)
        bOff[q] = (n0 + q * 32 + srow) * CIN + colsrc;
    const int ldsd = tid * 16;

#define STAGE(s_) do {                                                        \
    const int ij_  = (s_) >> 1;                                               \
    const int ck_  = ((s_) & 1) << 6;                                         \
    const int ii_  = ij_ / 3, jj_ = ij_ - 3 * ii_;                            \
    const int oa_  = (ii_ * WP + jj_) * CIN + ck_;                            \
    const int ob_  = ij_ * (OCH * CIN) + ck_;                                 \
    _Pragma("unroll") for (int q_ = 0; q_ < 8; ++q_)                          \
        gload16(xb + aOff[q_] + oa_, smem + q_ * 4096 + ldsd);                \
    _Pragma("unroll") for (int q_ = 0; q_ < 4; ++q_)                          \
        gload16(wb + bOff[q_] + ob_, smem + 32768 + q_ * 4096 + ldsd);        \
} while (0)

    // ---- compute-side constants ----
    const int wm  = wv >> 1;                  // 0..1 : rows [wm*128, +128)
    const int wn  = wv & 1;                   // 0..1 : cols [wn*64, +64)
    const int fr  = ln & 15;
    const int kby = (ln >> 4) * 16;
    const int swz = (ln & 7) << 4;

    f32x4 acc[8][4] = {};
    bf16x8 af[8], bf[4];

#define READK(kk) do {                                                        \
    _Pragma("unroll") for (int mi = 0; mi < 8; ++mi)                          \
        af[mi] = *(const bf16x8*)(smem +                                      \
            (wm*128 + mi*16 + fr)*128 + (((kk)*64 + kby) ^ swz));             \
    _Pragma("unroll") for (int ni = 0; ni < 4; ++ni)                          \
        bf[ni] = *(const bf16x8*)(smem + 32768 +                              \
            (wn*64 + ni*16 + fr)*128 + (((kk)*64 + kby) ^ swz));              \
} while (0)

#define MM32 do {                                                             \
    _Pragma("unroll") for (int mi = 0; mi < 8; ++mi)                          \
    _Pragma("unroll") for (int ni = 0; ni < 4; ++ni)                          \
        acc[mi][ni] = __builtin_amdgcn_mfma_f32_16x16x32_bf16(                \
            af[mi], bf[ni], acc[mi][ni], 0, 0, 0);                            \
} while (0)

#define LGKM0 do { asm volatile("s_waitcnt lgkmcnt(0)" ::: "memory");         \
                   __builtin_amdgcn_sched_barrier(0); } while (0)

    // ---- prologue ----
    STAGE(0);

#pragma unroll 1
    for (int s = 0; s < 18; ++s) {
        __syncthreads();                      // chunk-s data landed (drains vmcnt)
        READK(0);
        LGKM0;
        __builtin_amdgcn_s_setprio(1);
        MM32;
        __builtin_amdgcn_s_setprio(0);
        __builtin_amdgcn_sched_barrier(0);
        READK(1);
        LGKM0;
        __syncthreads();                      // all waves done reading buffer
        if (s < 17) STAGE(s + 1);             // async overwrite, overlaps MFMA
        __builtin_amdgcn_s_setprio(1);
        MM32;
        __builtin_amdgcn_s_setprio(0);
        __builtin_amdgcn_sched_barrier(0);
    }
#undef STAGE
#undef READK
#undef MM32
#undef LGKM0

    // ---- epilogue: C/D map col=ln&15 (n), row=(ln>>4)*4+reg (pixel) ----
    const int laneR4 = (ln >> 4) * 4;
    float bn[4];
#pragma unroll
    for (int ni = 0; ni < 4; ++ni)
        bn[ni] = bias[n0 + wn * 64 + ni * 16 + fr];

#pragma unroll
    for (int mi = 0; mi < 8; ++mi) {
        int p0 = m0 + wm * 128 + mi * 16 + laneR4;   // multiple of 4; 4 | HWSZ
        int b  = p0 / HWSZ;
        int hw = p0 - b * HWSZ;
#pragma unroll
        for (int ni = 0; ni < 4; ++ni) {
            int n = n0 + wn * 64 + ni * 16 + fr;
            float4 v;
            v.x = acc[mi][ni][0] + bn[ni];
            v.y = acc[mi][ni][1] + bn[ni];
            v.z = acc[mi][ni][2] + bn[ni];
            v.w = acc[mi][ni][3] + bn[ni];
            *(float4*)(out + ((size_t)(b * OCH + n) * HWSZ + hw)) = v;
        }
    }
}

extern "C" void kernel_launch(void* const* d_in, const int* in_sizes, int n_in,
                              void* d_out, int out_size, void* d_ws, size_t ws_size,
                              hipStream_t stream) {
    const float* x    = (const float*)d_in[0];
    const float* w    = (const float*)d_in[1];
    const float* bias = (const float*)d_in[2];
    float* out = (float*)d_out;

    char* ws = (char*)d_ws;
    __hip_bfloat16* xbuf = (__hip_bfloat16*)ws;                   // 27,557,888 B
    __hip_bfloat16* wbuf = (__hip_bfloat16*)(ws + 27557888);      //    589,824 B

    small_prep<<<1608, 256, 0, stream>>>(w, wbuf, xbuf);
    cast_transpose_x<<<dim3(98, 2, 32), dim3(256), 0, stream>>>(x, xbuf);
    conv_gemm<<<784, 256, 0, stream>>>(xbuf, wbuf, bias, out);
}